// Round 2
// baseline (37408.054 us; speedup 1.0000x reference)
//
#include <hip/hip_runtime.h>

// BiLSTM-CRF forward on MI355X.
//   wtrans:   transpose W_ih to [k][row]; bias sums.
//   gin:      embedding gather + input projection gin_d[t][1024] (reverse time-flipped).
//   lstm:     persistent 16-WG kernel, 8 WG/direction, waves fully independent.
//             h broadcast via L3 as atomic 8B (value,tag) pairs in a 2-slot ring:
//             consumer poll == data load (tag validates freshness), no flag RMW,
//             no store-ack, no __syncthreads.
//   feats:    [hf,hr] @ w_out^T + b_out.
//   viterbi:  single-wave exact DP (bitwise-identical op order to reference),
//             then 3-phase parallel backtrace via chunk-map composition.

#define SEQ  8192
#define EMBD 256
#define HD   256
#define G4   1024
#define NWG  8
#define NEGV -10000.0f

typedef unsigned int u32x4 __attribute__((ext_vector_type(4)));
typedef unsigned int u32x2 __attribute__((ext_vector_type(2)));

__device__ __forceinline__ float sigmf(float x) { return 1.0f / (1.0f + expf(-x)); }

// coherent (device-scope) 32B pair load: 4 (value,tag) pairs + wait
__device__ __forceinline__ void load_pairs(const void* p, u32x4& a, u32x4& b) {
    asm volatile("global_load_dwordx4 %0, %2, off sc0 sc1\n\t"
                 "global_load_dwordx4 %1, %2, off offset:16 sc0 sc1\n\t"
                 "s_waitcnt vmcnt(0)"
                 : "=&v"(a), "=&v"(b) : "v"(p) : "memory");
}
// coherent atomic 8B pair store (value,tag) — tag rides with data, no ack needed
__device__ __forceinline__ void store_pair(void* p, float h, unsigned tag) {
    u32x2 d; d[0] = __float_as_uint(h); d[1] = tag;
    asm volatile("global_store_dwordx2 %0, %1, off sc0 sc1" :: "v"(p), "v"(d) : "memory");
}

// ---------------------------------------------------------------- init (per launch: ring reset)
__global__ void init_kernel(unsigned long long* ring_f, unsigned long long* ring_r) {
    int i = threadIdx.x;                       // 256 threads
    unsigned long long v1 = ((unsigned long long)1u) << 32;   // h[0]=0.0f, tag=1
    ring_f[i] = v1; ring_f[256 + i] = 0ull;
    ring_r[i] = v1; ring_r[256 + i] = 0ull;
}

// ---------------------------------------------------------------- W_ih transpose + bias sums
__global__ void wtrans_kernel(const float* __restrict__ w_ih_f, const float* __restrict__ w_ih_r,
                              const float* __restrict__ b_ih_f, const float* __restrict__ b_hh_f,
                              const float* __restrict__ b_ih_r, const float* __restrict__ b_hh_r,
                              float* __restrict__ wt_f, float* __restrict__ wt_r,
                              float* __restrict__ bs_f, float* __restrict__ bs_r) {
    int row = blockIdx.x;          // 0..1023
    int k   = threadIdx.x;         // 0..255
    wt_f[(size_t)k * G4 + row] = w_ih_f[(size_t)row * EMBD + k];
    wt_r[(size_t)k * G4 + row] = w_ih_r[(size_t)row * EMBD + k];
    if (k == 0) {
        bs_f[row] = b_ih_f[row] + b_hh_f[row];
        bs_r[row] = b_ih_r[row] + b_hh_r[row];
    }
}

// ---------------------------------------------------------------- input projection
__global__ __launch_bounds__(256) void gin_kernel(
    const int* __restrict__ sentence, const float* __restrict__ emb,
    const float* __restrict__ wt_f, const float* __restrict__ wt_r,
    const float* __restrict__ bs_f, const float* __restrict__ bs_r,
    float* __restrict__ gin_f, float* __restrict__ gin_r)
{
    __shared__ float x_lds[32][EMBD];
    __shared__ int   sid_lds[32];
    int t0  = blockIdx.x * 32;
    int tid = threadIdx.x;
    if (tid < 32) sid_lds[tid] = sentence[t0 + tid];
    __syncthreads();
    for (int i = 0; i < 32; ++i)
        x_lds[i][tid] = emb[(size_t)sid_lds[i] * EMBD + tid];
    __syncthreads();

    float bsv[8];
#pragma unroll
    for (int m = 0; m < 4; ++m) bsv[m]     = bs_f[tid + 256 * m];
#pragma unroll
    for (int m = 0; m < 4; ++m) bsv[4 + m] = bs_r[tid + 256 * m];

    for (int tsub = 0; tsub < 4; ++tsub) {
        float acc[8][8];
#pragma unroll
        for (int m = 0; m < 8; ++m)
#pragma unroll
            for (int j = 0; j < 8; ++j) acc[m][j] = bsv[m];

        for (int k = 0; k < EMBD; ++k) {
            float xv[8];
#pragma unroll
            for (int j = 0; j < 8; ++j) xv[j] = x_lds[tsub * 8 + j][k];
#pragma unroll
            for (int m = 0; m < 8; ++m) {
                float wv = (m < 4) ? wt_f[(size_t)k * G4 + tid + 256 * m]
                                   : wt_r[(size_t)k * G4 + tid + 256 * (m - 4)];
#pragma unroll
                for (int j = 0; j < 8; ++j) acc[m][j] = fmaf(wv, xv[j], acc[m][j]);
            }
        }
#pragma unroll
        for (int m = 0; m < 8; ++m) {
            int row = tid + 256 * (m & 3);
#pragma unroll
            for (int j = 0; j < 8; ++j) {
                int t = t0 + tsub * 8 + j;
                if (m < 4) gin_f[(size_t)t * G4 + row] = acc[m][j];
                else       gin_r[(size_t)(SEQ - 1 - t) * G4 + row] = acc[m][j];
            }
        }
    }
}

// ---------------------------------------------------------------- persistent LSTM
// grid = 16 x 256. block b: dir=b&1, slice s=b>>1 (32 units, 128 gate rows).
// Waves fully independent: each wave loads all 256 (h,tag) pairs, validates tags,
// stages into its own LDS row, computes its 32 rows, publishes its 8 units.
__global__ __launch_bounds__(256, 1) void lstm_kernel(
    const float* __restrict__ w_hh_f, const float* __restrict__ w_hh_r,
    const float* __restrict__ gin_f, const float* __restrict__ gin_r,
    unsigned long long* ring_f, unsigned long long* ring_r,
    float* __restrict__ hcomp_f, float* __restrict__ hcomp_r)
{
    int b   = blockIdx.x;
    int dir = b & 1;
    int s   = b >> 1;
    const float* W   = dir ? w_hh_r : w_hh_f;
    const float* gin = dir ? gin_r  : gin_f;
    unsigned long long* ring = dir ? ring_r : ring_f;
    float* hcomp = dir ? hcomp_r : hcomp_f;

    int tid  = threadIdx.x;
    int wv   = tid >> 6;            // wave 0..3
    int lane = tid & 63;
    int r    = tid >> 1;            // local row 0..127 (= unit*4 + gate)
    int hh   = tid & 1;             // which half of the 256-dot
    int grow = (r & 3) * 256 + s * 32 + (r >> 2);   // global gate row [i|f|g|o]

    // resident weights: 128 f32 per thread
    float w[128];
    {
        const float4* wrow = reinterpret_cast<const float4*>(&W[(size_t)grow * HD + hh * 128]);
#pragma unroll
        for (int kk = 0; kk < 32; ++kk) {
            float4 v = wrow[kk];
            w[4 * kk + 0] = v.x; w[4 * kk + 1] = v.y;
            w[4 * kk + 2] = v.z; w[4 * kk + 3] = v.w;
        }
    }

    __shared__ float h_lds[4][256];      // per-wave staging, no cross-wave use

    float c    = 0.0f;
    int   unit = s * 32 + wv * 8 + (lane >> 3);
    bool  pub  = (lane & 7) == 0;        // 8 publisher lanes per wave

    for (int t = 0; t < SEQ; ++t) {
        float gval = gin[(size_t)t * G4 + grow];     // independent of h, issues early

        unsigned tagexp = (unsigned)(t + 1);
        const unsigned long long* slot = ring + (size_t)(t & 1) * 256 + 4 * lane;
        u32x4 pa, pb;
        for (;;) {
            load_pairs(slot, pa, pb);
            int ok = (pa[1] == tagexp) & (pa[3] == tagexp) &
                     (pb[1] == tagexp) & (pb[3] == tagexp);
            if (__all(ok)) break;
        }
        float4 hv;
        hv.x = __uint_as_float(pa[0]); hv.y = __uint_as_float(pa[2]);
        hv.z = __uint_as_float(pb[0]); hv.w = __uint_as_float(pb[2]);
        *reinterpret_cast<float4*>(&h_lds[wv][4 * lane]) = hv;   // own-wave LDS, in-order

        float a0 = 0.f, a1 = 0.f, a2 = 0.f, a3 = 0.f;
#pragma unroll
        for (int kk = 0; kk < 32; ++kk) {
            float4 h4 = *reinterpret_cast<const float4*>(&h_lds[wv][hh * 128 + 4 * kk]);
            a0 = fmaf(w[4 * kk + 0], h4.x, a0);
            a1 = fmaf(w[4 * kk + 1], h4.y, a1);
            a2 = fmaf(w[4 * kk + 2], h4.z, a2);
            a3 = fmaf(w[4 * kk + 3], h4.w, a3);
        }
        float tot = (a0 + a1) + (a2 + a3);
        tot += __shfl_xor(tot, 1);           // both half-lanes now hold full row sum
        float x  = tot + gval;               // gate pre-activation (even lanes meaningful)
        float xf = __shfl_xor(x, 2);         // lane 8u: f-gate (row 4u+1)
        float xg = __shfl_xor(x, 4);         // lane 8u: g-gate (row 4u+2)
        float xo = __shfl_xor(x, 6);         // lane 8u: o-gate (row 4u+3)

        if (pub) {
            float ig = sigmf(x), fg = sigmf(xf), gg = tanhf(xg), og = sigmf(xo);
            c = fg * c + ig * gg;
            float hval = og * tanhf(c);
            hcomp[(size_t)(t + 1) * HD + unit] = hval;           // history for feats
            store_pair(ring + (size_t)((t + 1) & 1) * 256 + unit, hval, (unsigned)(t + 2));
        }
    }
}

// ---------------------------------------------------------------- feats = [hf,hr] @ w_out^T + b
__global__ __launch_bounds__(256) void feats_kernel(
    const float* __restrict__ hf_buf, const float* __restrict__ hr_buf,
    const float* __restrict__ w_out, const float* __restrict__ b_out,
    float* __restrict__ feats)
{
    __shared__ __align__(16) float wt_lds[256][36];
    int tid = threadIdx.x;
    int t   = blockIdx.x * 256 + tid;

    float acc[32];
#pragma unroll
    for (int g = 0; g < 32; ++g) acc[g] = b_out[g];

    for (int half = 0; half < 2; ++half) {
        __syncthreads();
        for (int tag = 0; tag < 32; ++tag)
            wt_lds[tid][tag] = w_out[tag * 512 + half * 256 + tid];
        __syncthreads();

        const float* hsrc = (half == 0) ? &hf_buf[(size_t)(t + 1) * HD]
                                        : &hr_buf[(size_t)(SEQ - t) * HD];
        for (int k = 0; k < 256; k += 4) {
            float4 hv = *reinterpret_cast<const float4*>(&hsrc[k]);
#pragma unroll
            for (int kk = 0; kk < 4; ++kk) {
                float hx = (kk == 0) ? hv.x : (kk == 1) ? hv.y : (kk == 2) ? hv.z : hv.w;
#pragma unroll
                for (int q = 0; q < 8; ++q) {
                    float4 wv = *reinterpret_cast<const float4*>(&wt_lds[k + kk][4 * q]);
                    acc[4 * q + 0] = fmaf(hx, wv.x, acc[4 * q + 0]);
                    acc[4 * q + 1] = fmaf(hx, wv.y, acc[4 * q + 1]);
                    acc[4 * q + 2] = fmaf(hx, wv.z, acc[4 * q + 2]);
                    acc[4 * q + 3] = fmaf(hx, wv.w, acc[4 * q + 3]);
                }
            }
        }
    }
#pragma unroll
    for (int q = 0; q < 8; ++q) {
        float4 o;
        o.x = acc[4 * q + 0]; o.y = acc[4 * q + 1];
        o.z = acc[4 * q + 2]; o.w = acc[4 * q + 3];
        *reinterpret_cast<float4*>(&feats[(size_t)t * 32 + 4 * q]) = o;
    }
}

// ---------------------------------------------------------------- viterbi DP (1 wave, no barriers)
__global__ void viterbi_dp(const float* __restrict__ feats,
                           const float* __restrict__ trans,
                           unsigned char* __restrict__ bp,
                           float* __restrict__ out, int* __restrict__ best_ws)
{
    __shared__ float v[32];
    int tid = threadIdx.x, n = tid >> 1, ph = tid & 1;

    float T[16];
#pragma unroll
    for (int p = 0; p < 16; ++p) T[p] = trans[n * 32 + ph * 16 + p];

    if (tid < 32) v[tid] = (tid == 30) ? 0.0f : NEGV;   // START = 30
    __builtin_amdgcn_wave_barrier();

    float fcur = feats[n];
    for (int t = 0; t < SEQ; ++t) {
        float fnext = (t + 1 < SEQ) ? feats[(size_t)(t + 1) * 32 + n] : 0.0f;

        float vv[16];
        *reinterpret_cast<float4*>(&vv[0])  = *reinterpret_cast<const float4*>(&v[ph * 16 + 0]);
        *reinterpret_cast<float4*>(&vv[4])  = *reinterpret_cast<const float4*>(&v[ph * 16 + 4]);
        *reinterpret_cast<float4*>(&vv[8])  = *reinterpret_cast<const float4*>(&v[ph * 16 + 8]);
        *reinterpret_cast<float4*>(&vv[12]) = *reinterpret_cast<const float4*>(&v[ph * 16 + 12]);

        float s[16]; int id[16];
#pragma unroll
        for (int p = 0; p < 16; ++p) { s[p] = vv[p] + T[p]; id[p] = p; }
        // tournament: prefer LEFT (lower index) on ties — matches jnp.argmax
#pragma unroll
        for (int st = 1; st < 16; st <<= 1)
#pragma unroll
            for (int p = 0; p < 16; p += 2 * st) {
                bool rgt = s[p + st] > s[p];
                s[p]  = rgt ? s[p + st]  : s[p];
                id[p] = rgt ? id[p + st] : id[p];
            }
        float best = s[0]; int barg = ph * 16 + id[0];
        float ob = __shfl_xor(best, 1);
        int   oa = __shfl_xor(barg, 1);
        bool useOther = ph ? (ob >= best) : (ob > best);   // low half wins ties
        float m    = useOther ? ob : best;
        int   aarg = useOther ? oa : barg;

        __builtin_amdgcn_wave_barrier();
        if (ph == 0) {
            v[n] = m + fcur;
            bp[(size_t)t * 32 + n] = (unsigned char)aarg;
        }
        __builtin_amdgcn_wave_barrier();
        fcur = fnext;
    }

    float term; int idx;
    if (tid < 32) { term = v[tid] + trans[31 * 32 + tid]; idx = tid; }
    else          { term = -3.4e38f; idx = 63; }
#pragma unroll
    for (int off = 1; off < 32; off <<= 1) {
        float ot = __shfl_xor(term, off);
        int   oi = __shfl_xor(idx, off);
        if (ot > term || (ot == term && oi < idx)) { term = ot; idx = oi; }
    }
    if (tid == 0) { out[0] = term; best_ws[0] = idx; }
}

// ---------------------------------------------------------------- backtrace, 3 phases (exact)
// A: per 32-step chunk, compose backpointer maps: G_c(g) = bp[c*32](...bp[c*32+31](g))
__global__ void bt_chunks(const unsigned char* __restrict__ bp, unsigned char* __restrict__ G) {
    __shared__ unsigned char lbp[32][32];
    int c = blockIdx.x, tid = threadIdx.x;   // 64 threads
    reinterpret_cast<int4*>(lbp)[tid] = reinterpret_cast<const int4*>(bp + (size_t)c * 1024)[tid];
    __syncthreads();
    if (tid < 32) {
        int cur = tid;
#pragma unroll 8
        for (int i = 31; i >= 0; --i) cur = lbp[i][cur];
        G[c * 32 + tid] = (unsigned char)cur;
    }
}
// B: sequential suffix over 256 chunk maps -> end-tag per chunk
__global__ void bt_boundaries(const unsigned char* __restrict__ G, const int* __restrict__ best,
                              unsigned char* __restrict__ E) {
    __shared__ unsigned char lG[256 * 32];   // 8KB
    int tid = threadIdx.x;                   // 256 threads
    reinterpret_cast<int4*>(lG)[tid]       = reinterpret_cast<const int4*>(G)[tid];
    reinterpret_cast<int4*>(lG)[256 + tid] = reinterpret_cast<const int4*>(G)[256 + tid];
    __syncthreads();
    if (tid == 0) {
        int e = *best;                       // path[SEQ-1]
        E[255] = (unsigned char)e;
        for (int ch = 255; ch >= 1; --ch) { e = lG[ch * 32 + e]; E[ch - 1] = (unsigned char)e; }
    }
}
// C: per chunk, walk 32 steps from the chunk end-tag, emit path as float
__global__ void bt_emit(const unsigned char* __restrict__ bp, const unsigned char* __restrict__ E,
                        float* __restrict__ out) {
    __shared__ unsigned char lbp[32][32];
    int c = blockIdx.x, tid = threadIdx.x;   // 64 threads
    reinterpret_cast<int4*>(lbp)[tid] = reinterpret_cast<const int4*>(bp + (size_t)c * 1024)[tid];
    __syncthreads();
    if (tid == 0) {
        int tag = E[c];
        for (int i = 31; i >= 0; --i) {
            out[1 + (size_t)c * 32 + i] = (float)tag;
            tag = lbp[i][tag];
        }
    }
}

// ---------------------------------------------------------------- launch
extern "C" void kernel_launch(void* const* d_in, const int* in_sizes, int n_in,
                              void* d_out, int out_size, void* d_ws, size_t ws_size,
                              hipStream_t stream)
{
    const int*   sentence = (const int*)d_in[0];
    const float* emb      = (const float*)d_in[1];
    const float* w_ih_f   = (const float*)d_in[2];
    const float* w_hh_f   = (const float*)d_in[3];
    const float* b_ih_f   = (const float*)d_in[4];
    const float* b_hh_f   = (const float*)d_in[5];
    const float* w_ih_r   = (const float*)d_in[6];
    const float* w_hh_r   = (const float*)d_in[7];
    const float* b_ih_r   = (const float*)d_in[8];
    const float* b_hh_r   = (const float*)d_in[9];
    const float* w_out    = (const float*)d_in[10];
    const float* b_out    = (const float*)d_in[11];
    const float* trans    = (const float*)d_in[12];
    (void)in_sizes; (void)n_in; (void)out_size; (void)ws_size;

    char* ws = (char*)d_ws;
    size_t off = 0;
    auto alloc = [&](size_t bytes) -> void* {
        void* p = (void*)(ws + off);
        off += (bytes + 255) & ~(size_t)255;
        return p;
    };
    float* gin_f   = (float*)alloc((size_t)SEQ * G4 * 4);          // 32 MiB
    float* gin_r   = (float*)alloc((size_t)SEQ * G4 * 4);          // 32 MiB
    float* hcomp_f = (float*)alloc((size_t)(SEQ + 1) * HD * 4);    // 8 MiB
    float* hcomp_r = (float*)alloc((size_t)(SEQ + 1) * HD * 4);    // 8 MiB
    float* wt_f    = (float*)alloc((size_t)EMBD * G4 * 4);         // 1 MiB
    float* wt_r    = (float*)alloc((size_t)EMBD * G4 * 4);         // 1 MiB
    float* bs_f    = (float*)alloc(G4 * 4);
    float* bs_r    = (float*)alloc(G4 * 4);
    unsigned long long* ring_f = (unsigned long long*)alloc(2 * 256 * 8);  // 4 KiB
    unsigned long long* ring_r = (unsigned long long*)alloc(2 * 256 * 8);  // 4 KiB
    float* feats   = (float*)alloc((size_t)SEQ * 32 * 4);          // 1 MiB
    unsigned char* bp = (unsigned char*)alloc((size_t)SEQ * 32);   // 256 KiB
    unsigned char* G  = (unsigned char*)alloc(256 * 32);           // 8 KiB
    unsigned char* E  = (unsigned char*)alloc(256);
    int* best_ws      = (int*)alloc(256);

    init_kernel<<<1, 256, 0, stream>>>(ring_f, ring_r);
    wtrans_kernel<<<G4, 256, 0, stream>>>(w_ih_f, w_ih_r, b_ih_f, b_hh_f, b_ih_r, b_hh_r,
                                          wt_f, wt_r, bs_f, bs_r);
    gin_kernel<<<SEQ / 32, 256, 0, stream>>>(sentence, emb, wt_f, wt_r, bs_f, bs_r,
                                             gin_f, gin_r);
    lstm_kernel<<<2 * NWG, 256, 0, stream>>>(w_hh_f, w_hh_r, gin_f, gin_r,
                                             ring_f, ring_r, hcomp_f, hcomp_r);
    feats_kernel<<<SEQ / 256, 256, 0, stream>>>(hcomp_f, hcomp_r, w_out, b_out, feats);
    viterbi_dp<<<1, 64, 0, stream>>>(feats, trans, bp, (float*)d_out, best_ws);
    bt_chunks<<<256, 64, 0, stream>>>(bp, G);
    bt_boundaries<<<1, 256, 0, stream>>>(G, best_ws, E);
    bt_emit<<<256, 64, 0, stream>>>(bp, E, (float*)d_out);
}

// Round 4
// 23205.974 us; speedup vs baseline: 1.6120x; 1.6120x over previous
//
#include <hip/hip_runtime.h>

// BiLSTM-CRF forward on MI355X.
//   init:     ring tags + bias sums.
//   wtrans:   LDS-tiled transpose of W_ih to [k][row] (coalesced both sides).
//   gin:      embedding gather + input projection gin_d[t][1024] (reverse time-flipped).
//   lstm:     persistent 16-WG kernel (8 WG/dir), waves fully independent.
//             h broadcast as tagged 8B (value,tag) pairs at DEVICE coherence scope
//             (sc0 sc1 — proven; sc0-only deadlocked in R3). Consumer poll == data
//             load; per-lane partial re-poll; gin prefetch issued after poll.
//   feats:    [hf,hr] @ w_out^T + b_out.
//   viterbi:  R1's proven monolithic kernel (DP + serial backtrace).

#define SEQ  8192
#define EMBD 256
#define HD   256
#define G4   1024
#define NEGV -10000.0f

typedef unsigned int u32x4 __attribute__((ext_vector_type(4)));
typedef unsigned int u32x2 __attribute__((ext_vector_type(2)));

__device__ __forceinline__ float sigmf(float x) { return 1.0f / (1.0f + expf(-x)); }

// device-coherent 32B pair load: 4 (value,tag) pairs + wait (single asm: outputs
// defined after the internal waitcnt -> no hoist hazard)
__device__ __forceinline__ void load_pairs(const void* p, u32x4& a, u32x4& b) {
    asm volatile("global_load_dwordx4 %0, %2, off sc0 sc1\n\t"
                 "global_load_dwordx4 %1, %2, off offset:16 sc0 sc1\n\t"
                 "s_waitcnt vmcnt(0)"
                 : "=&v"(a), "=&v"(b) : "v"(p) : "memory");
}
// device-coherent atomic 8B (value,tag) store — tag rides with data, no ack needed
__device__ __forceinline__ void store_pair(void* p, float h, unsigned tag) {
    u32x2 d; d[0] = __float_as_uint(h); d[1] = tag;
    asm volatile("global_store_dwordx2 %0, %1, off sc0 sc1" :: "v"(p), "v"(d) : "memory");
}

// ---------------------------------------------------------------- init (per launch)
__global__ void init_kernel(unsigned long long* ring_f, unsigned long long* ring_r,
                            const float* __restrict__ b_ih_f, const float* __restrict__ b_hh_f,
                            const float* __restrict__ b_ih_r, const float* __restrict__ b_hh_r,
                            float* __restrict__ bs_f, float* __restrict__ bs_r) {
    int i = threadIdx.x;                       // 256 threads
    unsigned long long v1 = ((unsigned long long)1u) << 32;   // h[0]=0.0f, tag=1
    ring_f[i] = v1; ring_f[256 + i] = 0ull;
    ring_r[i] = v1; ring_r[256 + i] = 0ull;
#pragma unroll
    for (int m = 0; m < 4; ++m) {
        int row = i + 256 * m;
        bs_f[row] = b_ih_f[row] + b_hh_f[row];
        bs_r[row] = b_ih_r[row] + b_hh_r[row];
    }
}

// ---------------------------------------------------------------- W_ih transpose (tiled)
__global__ __launch_bounds__(256) void wtrans_kernel(
    const float* __restrict__ w_ih_f, const float* __restrict__ w_ih_r,
    float* __restrict__ wt_f, float* __restrict__ wt_r) {
    __shared__ float tile[32][257];
    int mat = blockIdx.x & 1;
    int r0  = (blockIdx.x >> 1) << 5;          // 0,32,...,992
    const float* src = mat ? w_ih_r : w_ih_f;
    float*       dst = mat ? wt_r   : wt_f;
    int tid = threadIdx.x;
    for (int r = 0; r < 32; ++r)
        tile[r][tid] = src[(size_t)(r0 + r) * EMBD + tid];
    __syncthreads();
    int row = tid & 31, kq = tid >> 5;
    for (int kb = 0; kb < EMBD; kb += 8) {
        int k = kb + kq;
        dst[(size_t)k * G4 + r0 + row] = tile[row][k];
    }
}

// ---------------------------------------------------------------- input projection
__global__ __launch_bounds__(256) void gin_kernel(
    const int* __restrict__ sentence, const float* __restrict__ emb,
    const float* __restrict__ wt_f, const float* __restrict__ wt_r,
    const float* __restrict__ bs_f, const float* __restrict__ bs_r,
    float* __restrict__ gin_f, float* __restrict__ gin_r)
{
    __shared__ float x_lds[32][EMBD];
    __shared__ int   sid_lds[32];
    int t0  = blockIdx.x * 32;
    int tid = threadIdx.x;
    if (tid < 32) sid_lds[tid] = sentence[t0 + tid];
    __syncthreads();
    for (int i = 0; i < 32; ++i)
        x_lds[i][tid] = emb[(size_t)sid_lds[i] * EMBD + tid];
    __syncthreads();

    float bsv[8];
#pragma unroll
    for (int m = 0; m < 4; ++m) bsv[m]     = bs_f[tid + 256 * m];
#pragma unroll
    for (int m = 0; m < 4; ++m) bsv[4 + m] = bs_r[tid + 256 * m];

    for (int tsub = 0; tsub < 4; ++tsub) {
        float acc[8][8];
#pragma unroll
        for (int m = 0; m < 8; ++m)
#pragma unroll
            for (int j = 0; j < 8; ++j) acc[m][j] = bsv[m];

        for (int k = 0; k < EMBD; ++k) {
            float xv[8];
#pragma unroll
            for (int j = 0; j < 8; ++j) xv[j] = x_lds[tsub * 8 + j][k];
#pragma unroll
            for (int m = 0; m < 8; ++m) {
                float wv = (m < 4) ? wt_f[(size_t)k * G4 + tid + 256 * m]
                                   : wt_r[(size_t)k * G4 + tid + 256 * (m - 4)];
#pragma unroll
                for (int j = 0; j < 8; ++j) acc[m][j] = fmaf(wv, xv[j], acc[m][j]);
            }
        }
#pragma unroll
        for (int m = 0; m < 8; ++m) {
            int row = tid + 256 * (m & 3);
#pragma unroll
            for (int j = 0; j < 8; ++j) {
                int t = t0 + tsub * 8 + j;
                if (m < 4) gin_f[(size_t)t * G4 + row] = acc[m][j];
                else       gin_r[(size_t)(SEQ - 1 - t) * G4 + row] = acc[m][j];
            }
        }
    }
}

// ---------------------------------------------------------------- persistent LSTM
// grid = 16 x 256. block b: dir=b&1, slice s=b>>1 (32 units, 128 gate rows).
// Waves fully independent; no __syncthreads in the step loop.
__global__ __launch_bounds__(256, 1) void lstm_kernel(
    const float* __restrict__ w_hh_f, const float* __restrict__ w_hh_r,
    const float* __restrict__ gin_f, const float* __restrict__ gin_r,
    unsigned long long* ring_f, unsigned long long* ring_r,
    float* __restrict__ hcomp_f, float* __restrict__ hcomp_r)
{
    int b   = blockIdx.x;
    int dir = b & 1;
    int s   = b >> 1;
    const float* W   = dir ? w_hh_r : w_hh_f;
    const float* gin = dir ? gin_r  : gin_f;
    unsigned long long* ring = dir ? ring_r : ring_f;
    float* hcomp = dir ? hcomp_r : hcomp_f;

    int tid  = threadIdx.x;
    int wv   = tid >> 6;            // wave 0..3
    int lane = tid & 63;
    int r    = tid >> 1;            // local row 0..127 (= unit*4 + gate)
    int hh   = tid & 1;             // which half of the 256-dot
    int grow = (r & 3) * 256 + s * 32 + (r >> 2);   // global gate row [i|f|g|o]

    // resident weights: 128 f32 per thread
    float w[128];
    {
        const float4* wrow = reinterpret_cast<const float4*>(&W[(size_t)grow * HD + hh * 128]);
#pragma unroll
        for (int kk = 0; kk < 32; ++kk) {
            float4 v = wrow[kk];
            w[4 * kk + 0] = v.x; w[4 * kk + 1] = v.y;
            w[4 * kk + 2] = v.z; w[4 * kk + 3] = v.w;
        }
    }

    __shared__ float h_lds[4][256];      // per-wave staging, no cross-wave use

    float c    = 0.0f;
    int   unit = s * 32 + wv * 8 + (lane >> 3);
    bool  pub  = (lane & 7) == 0;        // 8 publisher lanes per wave

    float gcur = gin[grow];              // step-0 input-part preactivation

    for (int t = 0; t < SEQ; ++t) {
        unsigned tagexp = (unsigned)(t + 1);
        const unsigned long long* slot = ring + (size_t)(t & 1) * 256 + 4 * lane;
        u32x4 pa, pb;
        load_pairs(slot, pa, pb);
        int ok = (pa[1] == tagexp) & (pa[3] == tagexp) &
                 (pb[1] == tagexp) & (pb[3] == tagexp);
        while (!__all(ok)) {
            if (!ok) load_pairs(slot, pa, pb);   // exec-masked: valid lanes skip
            ok = (pa[1] == tagexp) & (pa[3] == tagexp) &
                 (pb[1] == tagexp) & (pb[3] == tagexp);
        }

        float4 hv;
        hv.x = __uint_as_float(pa[0]); hv.y = __uint_as_float(pa[2]);
        hv.z = __uint_as_float(pb[0]); hv.w = __uint_as_float(pb[2]);
        *reinterpret_cast<float4*>(&h_lds[wv][4 * lane]) = hv;   // own-wave LDS

        // prefetch next step's input preactivation AFTER poll success:
        // overlaps dot+publish+next poll (>1500cy) -> never extends a wait.
        int tn = (t + 1 < SEQ) ? (t + 1) : (SEQ - 1);
        float gnext = gin[(size_t)tn * G4 + grow];

        float a0 = 0.f, a1 = 0.f, a2 = 0.f, a3 = 0.f;
#pragma unroll
        for (int kk = 0; kk < 32; ++kk) {
            float4 h4 = *reinterpret_cast<const float4*>(&h_lds[wv][hh * 128 + 4 * kk]);
            a0 = fmaf(w[4 * kk + 0], h4.x, a0);
            a1 = fmaf(w[4 * kk + 1], h4.y, a1);
            a2 = fmaf(w[4 * kk + 2], h4.z, a2);
            a3 = fmaf(w[4 * kk + 3], h4.w, a3);
        }
        float tot = (a0 + a1) + (a2 + a3);
        tot += __shfl_xor(tot, 1);           // both half-lanes hold full row sum
        float x  = tot + gcur;               // gate pre-activation
        float xf = __shfl_xor(x, 2);         // lane 8u: f-gate
        float xg = __shfl_xor(x, 4);         // lane 8u: g-gate
        float xo = __shfl_xor(x, 6);         // lane 8u: o-gate

        if (pub) {
            float ig = sigmf(x), fg = sigmf(xf), gg = tanhf(xg), og = sigmf(xo);
            c = fg * c + ig * gg;
            float hval = og * tanhf(c);
            // publish FIRST (critical path), then history store
            store_pair(ring + (size_t)((t + 1) & 1) * 256 + unit, hval, (unsigned)(t + 2));
            hcomp[(size_t)(t + 1) * HD + unit] = hval;
        }
        gcur = gnext;
    }
}

// ---------------------------------------------------------------- feats = [hf,hr] @ w_out^T + b
__global__ __launch_bounds__(256) void feats_kernel(
    const float* __restrict__ hf_buf, const float* __restrict__ hr_buf,
    const float* __restrict__ w_out, const float* __restrict__ b_out,
    float* __restrict__ feats)
{
    __shared__ __align__(16) float wt_lds[256][36];
    int tid = threadIdx.x;
    int t   = blockIdx.x * 256 + tid;

    float acc[32];
#pragma unroll
    for (int g = 0; g < 32; ++g) acc[g] = b_out[g];

    for (int half = 0; half < 2; ++half) {
        __syncthreads();
        for (int tag = 0; tag < 32; ++tag)
            wt_lds[tid][tag] = w_out[tag * 512 + half * 256 + tid];
        __syncthreads();

        const float* hsrc = (half == 0) ? &hf_buf[(size_t)(t + 1) * HD]
                                        : &hr_buf[(size_t)(SEQ - t) * HD];
        for (int k = 0; k < 256; k += 4) {
            float4 hv = *reinterpret_cast<const float4*>(&hsrc[k]);
#pragma unroll
            for (int kk = 0; kk < 4; ++kk) {
                float hx = (kk == 0) ? hv.x : (kk == 1) ? hv.y : (kk == 2) ? hv.z : hv.w;
#pragma unroll
                for (int q = 0; q < 8; ++q) {
                    float4 wv = *reinterpret_cast<const float4*>(&wt_lds[k + kk][4 * q]);
                    acc[4 * q + 0] = fmaf(hx, wv.x, acc[4 * q + 0]);
                    acc[4 * q + 1] = fmaf(hx, wv.y, acc[4 * q + 1]);
                    acc[4 * q + 2] = fmaf(hx, wv.z, acc[4 * q + 2]);
                    acc[4 * q + 3] = fmaf(hx, wv.w, acc[4 * q + 3]);
                }
            }
        }
    }
#pragma unroll
    for (int q = 0; q < 8; ++q) {
        float4 o;
        o.x = acc[4 * q + 0]; o.y = acc[4 * q + 1];
        o.z = acc[4 * q + 2]; o.w = acc[4 * q + 3];
        *reinterpret_cast<float4*>(&feats[(size_t)t * 32 + 4 * q]) = o;
    }
}

// ---------------------------------------------------------------- viterbi + backtrace (R1, proven)
__global__ void viterbi_kernel(const float* __restrict__ feats,
                               const float* __restrict__ transitions,
                               unsigned char* __restrict__ bp,
                               float* __restrict__ out)
{
    __shared__ float v[32];
    int tid = threadIdx.x;
    int n = tid >> 1, ph = tid & 1;

    float T[16];
#pragma unroll
    for (int p = 0; p < 16; ++p) T[p] = transitions[n * 32 + ph * 16 + p];

    if (tid < 32) v[tid] = (tid == 30) ? 0.0f : NEGV;   // START = 30
    __syncthreads();

    float fcur = feats[n];
    for (int t = 0; t < SEQ; ++t) {
        float fnext = (t + 1 < SEQ) ? feats[(size_t)(t + 1) * 32 + n] : 0.0f;

        float best = -3.4e38f; int barg = 0;
#pragma unroll
        for (int p = 0; p < 16; ++p) {
            float sc = v[ph * 16 + p] + T[p];
            if (sc > best) { best = sc; barg = ph * 16 + p; }   // strict > keeps first max
        }
        float ob = __shfl_xor(best, 1);
        int   oa = __shfl_xor(barg, 1);
        // jnp.argmax tie-break = lowest index: low half wins ties
        bool useOther = ph ? (ob >= best) : (ob > best);
        float m = useOther ? ob : best;
        int   a = useOther ? oa : barg;

        __syncthreads();
        if (ph == 0) {
            v[n] = m + fcur;
            bp[(size_t)t * 32 + n] = (unsigned char)a;
        }
        __syncthreads();
        fcur = fnext;
    }

    // terminal = v + transitions[STOP]; argmax with lowest-index tie-break
    float term; int idx;
    if (tid < 32) { term = v[tid] + transitions[31 * 32 + tid]; idx = tid; }
    else          { term = -3.4e38f; idx = 63; }
#pragma unroll
    for (int off = 1; off < 32; off <<= 1) {
        float ot = __shfl_xor(term, off);
        int   oi = __shfl_xor(idx, off);
        if (ot > term || (ot == term && oi < idx)) { term = ot; idx = oi; }
    }
    if (tid == 0) {
        out[0] = term;
        int tag = idx;
        out[1 + (SEQ - 1)] = (float)tag;
        for (int t = SEQ - 2; t >= 0; --t) {
            tag = bp[(size_t)(t + 1) * 32 + tag];
            out[1 + t] = (float)tag;
        }
    }
}

// ---------------------------------------------------------------- launch
extern "C" void kernel_launch(void* const* d_in, const int* in_sizes, int n_in,
                              void* d_out, int out_size, void* d_ws, size_t ws_size,
                              hipStream_t stream)
{
    const int*   sentence = (const int*)d_in[0];
    const float* emb      = (const float*)d_in[1];
    const float* w_ih_f   = (const float*)d_in[2];
    const float* w_hh_f   = (const float*)d_in[3];
    const float* b_ih_f   = (const float*)d_in[4];
    const float* b_hh_f   = (const float*)d_in[5];
    const float* w_ih_r   = (const float*)d_in[6];
    const float* w_hh_r   = (const float*)d_in[7];
    const float* b_ih_r   = (const float*)d_in[8];
    const float* b_hh_r   = (const float*)d_in[9];
    const float* w_out    = (const float*)d_in[10];
    const float* b_out    = (const float*)d_in[11];
    const float* trans    = (const float*)d_in[12];
    (void)in_sizes; (void)n_in; (void)out_size; (void)ws_size;

    char* ws = (char*)d_ws;
    size_t off = 0;
    auto alloc = [&](size_t bytes) -> void* {
        void* p = (void*)(ws + off);
        off += (bytes + 255) & ~(size_t)255;
        return p;
    };
    float* gin_f   = (float*)alloc((size_t)SEQ * G4 * 4);          // 32 MiB
    float* gin_r   = (float*)alloc((size_t)SEQ * G4 * 4);          // 32 MiB
    float* hcomp_f = (float*)alloc((size_t)(SEQ + 1) * HD * 4);    // 8 MiB
    float* hcomp_r = (float*)alloc((size_t)(SEQ + 1) * HD * 4);    // 8 MiB
    float* wt_f    = (float*)alloc((size_t)EMBD * G4 * 4);         // 1 MiB
    float* wt_r    = (float*)alloc((size_t)EMBD * G4 * 4);         // 1 MiB
    float* bs_f    = (float*)alloc(G4 * 4);
    float* bs_r    = (float*)alloc(G4 * 4);
    unsigned long long* ring_f = (unsigned long long*)alloc(2 * 256 * 8);
    unsigned long long* ring_r = (unsigned long long*)alloc(2 * 256 * 8);
    float* feats   = (float*)alloc((size_t)SEQ * 32 * 4);          // 1 MiB
    unsigned char* bp = (unsigned char*)alloc((size_t)SEQ * 32);   // 256 KiB

    init_kernel<<<1, 256, 0, stream>>>(ring_f, ring_r,
                                       b_ih_f, b_hh_f, b_ih_r, b_hh_r, bs_f, bs_r);
    wtrans_kernel<<<64, 256, 0, stream>>>(w_ih_f, w_ih_r, wt_f, wt_r);
    gin_kernel<<<SEQ / 32, 256, 0, stream>>>(sentence, emb, wt_f, wt_r, bs_f, bs_r,
                                             gin_f, gin_r);
    lstm_kernel<<<16, 256, 0, stream>>>(w_hh_f, w_hh_r, gin_f, gin_r,
                                        ring_f, ring_r, hcomp_f, hcomp_r);
    feats_kernel<<<SEQ / 256, 256, 0, stream>>>(hcomp_f, hcomp_r, w_out, b_out, feats);
    viterbi_kernel<<<1, 64, 0, stream>>>(feats, trans, bp, (float*)d_out);
}